// Round 11
// baseline (276.201 us; speedup 1.0000x reference)
//
#include <hip/hip_runtime.h>

static constexpr int B_ROWS  = 262144;
static constexpr int D       = 256;
static constexpr int NSAMP   = 5;
static constexpr int BLOCK   = 256;           // 4 waves
static constexpr int NBLOCKS = 2048;          // 8192 waves x 32 rows/wave
static constexpr int WPB     = BLOCK / 64;
static constexpr int GPW     = 16;            // rows per wave-iteration (4-lane groups)

// log(max(sigmoid(x), eps))   = -min(log(1+e^{-x}), -ln eps)
// log(max(sigmoid(-x), 0.75)) = -min(log(1+e^{x}),  -ln 0.75)
static constexpr float NEG_LN_EPS  = 20.723265836946411f;   // -ln(1e-9)
static constexpr float NEG_LN_BETA = 0.28768207245178085f;  // -ln(0.75)

__device__ __forceinline__ float dot4(const float4 a, const float4 b) {
    return a.x * b.x + a.y * b.y + a.z * b.z + a.w * b.w;
}

__global__ __launch_bounds__(BLOCK) void sgns_main(
    const float* __restrict__ ctx, const float* __restrict__ tgt,
    const float* __restrict__ emb, const int* __restrict__ neg_idx,
    float* __restrict__ partials, unsigned int* __restrict__ counter,
    float* __restrict__ out)
{
    __shared__ float smp[NSAMP][D];   // 5 KB; group-broadcast reads, conflict-free
    for (int i = threadIdx.x; i < NSAMP * D; i += BLOCK) {
        const int s = i >> 8, c = i & (D - 1);
        smp[s][c] = emb[(size_t)neg_idx[s] * D + c];
    }
    __syncthreads();

    const int lane = threadIdx.x & 63;
    const int wid  = threadIdx.x >> 6;
    const int sub  = lane & 3;        // position within 4-lane group
    const int grp  = lane >> 2;       // 0..15 -> which row
    const int gwave  = blockIdx.x * WPB + wid;
    const int nwaves = NBLOCKS * WPB;

    float acc = 0.0f;
    for (int rbase = gwave * GPW; rbase < B_ROWS; rbase += nwaves * GPW) {
        const float* cp = ctx + (size_t)(rbase + grp) * D + sub * 4;
        const float* tp = tgt + (size_t)(rbase + grp) * D + sub * 4;

        float d0 = 0.f, d1 = 0.f, d2 = 0.f, d3 = 0.f, d4 = 0.f, d5 = 0.f;
#pragma unroll 4
        for (int m = 0; m < 16; ++m) {
            const float4 c4 = *reinterpret_cast<const float4*>(cp + m * 16);
            const float4 t4 = *reinterpret_cast<const float4*>(tp + m * 16);
            const int sc = m * 16 + sub * 4;
            const float4 s0 = *reinterpret_cast<const float4*>(&smp[0][sc]);
            const float4 s1 = *reinterpret_cast<const float4*>(&smp[1][sc]);
            const float4 s2 = *reinterpret_cast<const float4*>(&smp[2][sc]);
            const float4 s3 = *reinterpret_cast<const float4*>(&smp[3][sc]);
            const float4 s4 = *reinterpret_cast<const float4*>(&smp[4][sc]);
            d0 += dot4(c4, t4);
            d1 += dot4(c4, s0);
            d2 += dot4(c4, s1);
            d3 += dot4(c4, s2);
            d4 += dot4(c4, s3);
            d5 += dot4(c4, s4);
        }

        // Reduce across the 4-lane group only (offsets 1,2 -> quad-perm DPP).
        d0 += __shfl_xor(d0, 1, 64); d0 += __shfl_xor(d0, 2, 64);
        d1 += __shfl_xor(d1, 1, 64); d1 += __shfl_xor(d1, 2, 64);
        d2 += __shfl_xor(d2, 1, 64); d2 += __shfl_xor(d2, 2, 64);
        d3 += __shfl_xor(d3, 1, 64); d3 += __shfl_xor(d3, 2, 64);
        d4 += __shfl_xor(d4, 1, 64); d4 += __shfl_xor(d4, 2, 64);
        d5 += __shfl_xor(d5, 1, 64); d5 += __shfl_xor(d5, 2, 64);

        float row_loss = -fminf(__logf(1.0f + __expf(-d0)), NEG_LN_EPS);
        row_loss -= fminf(__logf(1.0f + __expf(d1)), NEG_LN_BETA);
        row_loss -= fminf(__logf(1.0f + __expf(d2)), NEG_LN_BETA);
        row_loss -= fminf(__logf(1.0f + __expf(d3)), NEG_LN_BETA);
        row_loss -= fminf(__logf(1.0f + __expf(d4)), NEG_LN_BETA);
        row_loss -= fminf(__logf(1.0f + __expf(d5)), NEG_LN_BETA);
        acc += row_loss;   // duplicated 4x within each group; corrected below
    }

    // Full-wave reduce (once per wave). Each row counted 4x.
#pragma unroll
    for (int off = 32; off > 0; off >>= 1) acc += __shfl_xor(acc, off, 64);
    acc *= 0.25f;

    __shared__ float blk[WPB];
    if (lane == 0) blk[wid] = acc;
    __syncthreads();

    // Fused finalization (replaces the second kernel): publish this block's
    // partial with agent-scope release, count arrivals, and let the LAST block
    // reduce all partials in a FIXED order (bitwise-deterministic regardless of
    // which block finalizes). counter is memset to 0 each call (captured
    // hipMemsetAsync), so replays are deterministic. G16: agent-scope
    // atomics for cross-XCD visibility.
    __shared__ int last_flag;
    if (threadIdx.x == 0) {
        float s = 0.0f;
#pragma unroll
        for (int i = 0; i < WPB; ++i) s += blk[i];
        __hip_atomic_store(&partials[blockIdx.x], s, __ATOMIC_RELEASE,
                           __HIP_MEMORY_SCOPE_AGENT);
        const unsigned int old = __hip_atomic_fetch_add(
            counter, 1u, __ATOMIC_ACQ_REL, __HIP_MEMORY_SCOPE_AGENT);
        last_flag = (old == (unsigned int)(NBLOCKS - 1));
    }
    __syncthreads();

    if (last_flag) {   // block-uniform
        float t = 0.0f;
        for (int i = threadIdx.x; i < NBLOCKS; i += BLOCK)
            t += __hip_atomic_load(&partials[i], __ATOMIC_RELAXED,
                                   __HIP_MEMORY_SCOPE_AGENT);
#pragma unroll
        for (int off = 32; off > 0; off >>= 1) t += __shfl_xor(t, off, 64);
        __shared__ float fin[WPB];
        if (lane == 0) fin[wid] = t;
        __syncthreads();
        if (threadIdx.x == 0) {
            float s = 0.0f;
#pragma unroll
            for (int i = 0; i < WPB; ++i) s += fin[i];
            out[0] = s;
        }
    }
}

extern "C" void kernel_launch(void* const* d_in, const int* in_sizes, int n_in,
                              void* d_out, int out_size, void* d_ws, size_t ws_size,
                              hipStream_t stream) {
    const float* ctx     = (const float*)d_in[0];
    const float* tgt     = (const float*)d_in[1];
    const float* emb     = (const float*)d_in[2];
    const int*   neg_idx = (const int*)d_in[3];
    float* out      = (float*)d_out;
    float* partials = (float*)d_ws;                       // NBLOCKS floats = 8 KB
    unsigned int* counter = (unsigned int*)((char*)d_ws + NBLOCKS * sizeof(float));

    // Zero the arrival counter every call (captured as a graph memset node)
    // so replays are deterministic.
    hipMemsetAsync(counter, 0, sizeof(unsigned int), stream);

    sgns_main<<<NBLOCKS, BLOCK, 0, stream>>>(ctx, tgt, emb, neg_idx,
                                             partials, counter, out);
}

// Round 12
// 109.908 us; speedup vs baseline: 2.5130x; 2.5130x over previous
//
#include <hip/hip_runtime.h>

static constexpr int B_ROWS  = 262144;
static constexpr int D       = 256;
static constexpr int NSAMP   = 5;
static constexpr int BLOCK   = 256;           // 4 waves
static constexpr int NBLOCKS = 4096;          // 16384 waves x 16 rows = 262144 (1 iter/wave)
static constexpr int WPB     = BLOCK / 64;
static constexpr int GPW     = 16;            // rows per wave-iteration (4-lane groups)

// log(max(sigmoid(x), eps))   = -min(log(1+e^{-x}), -ln eps)
// log(max(sigmoid(-x), 0.75)) = -min(log(1+e^{x}),  -ln 0.75)
static constexpr float NEG_LN_EPS  = 20.723265836946411f;   // -ln(1e-9)
static constexpr float NEG_LN_BETA = 0.28768207245178085f;  // -ln(0.75)

__device__ __forceinline__ float dot4(const float4 a, const float4 b) {
    return a.x * b.x + a.y * b.y + a.z * b.z + a.w * b.w;
}

__global__ __launch_bounds__(BLOCK) void sgns_main(
    const float* __restrict__ ctx, const float* __restrict__ tgt,
    const float* __restrict__ emb, const int* __restrict__ neg_idx,
    float* __restrict__ partials)
{
    __shared__ float smp[NSAMP][D];   // 5 KB; group-broadcast reads, conflict-free
    for (int i = threadIdx.x; i < NSAMP * D; i += BLOCK) {
        const int s = i >> 8, c = i & (D - 1);
        smp[s][c] = emb[(size_t)neg_idx[s] * D + c];
    }
    __syncthreads();

    const int lane = threadIdx.x & 63;
    const int wid  = threadIdx.x >> 6;
    const int sub  = lane & 3;        // position within 4-lane group
    const int grp  = lane >> 2;       // 0..15 -> which row
    const int gwave  = blockIdx.x * WPB + wid;
    const int nwaves = NBLOCKS * WPB;

    float acc = 0.0f;
    for (int rbase = gwave * GPW; rbase < B_ROWS; rbase += nwaves * GPW) {
        const float* cp = ctx + (size_t)(rbase + grp) * D + sub * 4;
        const float* tp = tgt + (size_t)(rbase + grp) * D + sub * 4;

        float d0 = 0.f, d1 = 0.f, d2 = 0.f, d3 = 0.f, d4 = 0.f, d5 = 0.f;
#pragma unroll 4
        for (int m = 0; m < 16; ++m) {
            const float4 c4 = *reinterpret_cast<const float4*>(cp + m * 16);
            const float4 t4 = *reinterpret_cast<const float4*>(tp + m * 16);
            const int sc = m * 16 + sub * 4;
            const float4 s0 = *reinterpret_cast<const float4*>(&smp[0][sc]);
            const float4 s1 = *reinterpret_cast<const float4*>(&smp[1][sc]);
            const float4 s2 = *reinterpret_cast<const float4*>(&smp[2][sc]);
            const float4 s3 = *reinterpret_cast<const float4*>(&smp[3][sc]);
            const float4 s4 = *reinterpret_cast<const float4*>(&smp[4][sc]);
            d0 += dot4(c4, t4);
            d1 += dot4(c4, s0);
            d2 += dot4(c4, s1);
            d3 += dot4(c4, s2);
            d4 += dot4(c4, s3);
            d5 += dot4(c4, s4);
        }

        // Reduce across the 4-lane group only (offsets 1,2 -> quad-perm DPP).
        d0 += __shfl_xor(d0, 1, 64); d0 += __shfl_xor(d0, 2, 64);
        d1 += __shfl_xor(d1, 1, 64); d1 += __shfl_xor(d1, 2, 64);
        d2 += __shfl_xor(d2, 1, 64); d2 += __shfl_xor(d2, 2, 64);
        d3 += __shfl_xor(d3, 1, 64); d3 += __shfl_xor(d3, 2, 64);
        d4 += __shfl_xor(d4, 1, 64); d4 += __shfl_xor(d4, 2, 64);
        d5 += __shfl_xor(d5, 1, 64); d5 += __shfl_xor(d5, 2, 64);

        float row_loss = -fminf(__logf(1.0f + __expf(-d0)), NEG_LN_EPS);
        row_loss -= fminf(__logf(1.0f + __expf(d1)), NEG_LN_BETA);
        row_loss -= fminf(__logf(1.0f + __expf(d2)), NEG_LN_BETA);
        row_loss -= fminf(__logf(1.0f + __expf(d3)), NEG_LN_BETA);
        row_loss -= fminf(__logf(1.0f + __expf(d4)), NEG_LN_BETA);
        row_loss -= fminf(__logf(1.0f + __expf(d5)), NEG_LN_BETA);
        acc += row_loss;   // duplicated 4x within each group; corrected below
    }

    // Full-wave reduce (once per wave). Each row counted 4x.
#pragma unroll
    for (int off = 32; off > 0; off >>= 1) acc += __shfl_xor(acc, off, 64);
    acc *= 0.25f;

    __shared__ float blk[WPB];
    if (lane == 0) blk[wid] = acc;
    __syncthreads();
    if (threadIdx.x == 0) {
        float s = 0.0f;
#pragma unroll
        for (int i = 0; i < WPB; ++i) s += blk[i];
        partials[blockIdx.x] = s;
    }
}

__global__ __launch_bounds__(256) void sgns_reduce(
    const float* __restrict__ partials, float* __restrict__ out)
{
    float s = 0.0f;
    for (int i = threadIdx.x; i < NBLOCKS; i += 256) s += partials[i];
#pragma unroll
    for (int off = 32; off > 0; off >>= 1) s += __shfl_xor(s, off, 64);
    __shared__ float lds[4];
    if ((threadIdx.x & 63) == 0) lds[threadIdx.x >> 6] = s;
    __syncthreads();
    if (threadIdx.x == 0) out[0] = lds[0] + lds[1] + lds[2] + lds[3];
}

extern "C" void kernel_launch(void* const* d_in, const int* in_sizes, int n_in,
                              void* d_out, int out_size, void* d_ws, size_t ws_size,
                              hipStream_t stream) {
    const float* ctx     = (const float*)d_in[0];
    const float* tgt     = (const float*)d_in[1];
    const float* emb     = (const float*)d_in[2];
    const int*   neg_idx = (const int*)d_in[3];
    float* out      = (float*)d_out;
    float* partials = (float*)d_ws;  // NBLOCKS floats = 16 KB

    sgns_main<<<NBLOCKS, BLOCK, 0, stream>>>(ctx, tgt, emb, neg_idx, partials);
    sgns_reduce<<<1, 256, 0, stream>>>(partials, out);
}